// Round 1
// baseline (585.903 us; speedup 1.0000x reference)
//
#include <hip/hip_runtime.h>
#include <stdint.h>

// Problem constants (fixed by setup_inputs)
#define D_F    128            // feature dim (all layers)
#define NGRAPH 16             // B
#define SEQ    512            // S
#define NTOK   8              // NUM_TOKEN
#define EMBED  4096

typedef __bf16 bf16_t;
typedef __attribute__((ext_vector_type(8))) bf16_t bf16x8;
typedef __attribute__((ext_vector_type(4))) float f32x4;

union U16B { uint4 u; bf16x8 b; };

static __device__ __forceinline__ unsigned short f2bf(float f) {
    unsigned int u = __float_as_uint(f);
    u += 0x7fffu + ((u >> 16) & 1u);          // round-to-nearest-even
    return (unsigned short)(u >> 16);
}
static __device__ __forceinline__ float bf2f(unsigned short s) {
    return __uint_as_float(((unsigned int)s) << 16);
}

// ---------------------------------------------------------------- CSR build
__global__ __launch_bounds__(256) void kDeg(const int* __restrict__ dst,
                                            int* __restrict__ deg, int E) {
    int e = blockIdx.x * 256 + threadIdx.x;
    if (e < E) atomicAdd(&deg[dst[e]], 1);
}

__global__ __launch_bounds__(1024) void kScan(const int* __restrict__ deg,
                                              int* __restrict__ rowptr, int n) {
    __shared__ int ls[1024];
    int t = threadIdx.x;
    int chunk = (n + 1023) / 1024;
    int s0 = t * chunk, s1 = s0 + chunk; if (s1 > n) s1 = n; if (s0 > n) s0 = n;
    int s = 0;
    for (int i = s0; i < s1; ++i) s += deg[i];
    ls[t] = s; __syncthreads();
    for (int off = 1; off < 1024; off <<= 1) {
        int v = (t >= off) ? ls[t - off] : 0;
        __syncthreads();
        ls[t] += v;
        __syncthreads();
    }
    int run = ls[t] - s;              // exclusive prefix at s0
    for (int i = s0; i < s1; ++i) { rowptr[i] = run; run += deg[i]; }
    if (s1 == n && s0 <= n) rowptr[n] = run;  // total (same value from all writers)
}

__global__ __launch_bounds__(256) void kFill(const int* __restrict__ src,
                                             const int* __restrict__ dst,
                                             const int* __restrict__ rowptr,
                                             int* __restrict__ fill,
                                             int* __restrict__ colidx, int E) {
    int e = blockIdx.x * 256 + threadIdx.x;
    if (e < E) {
        int d = dst[e];
        int pos = atomicAdd(&fill[d], 1);
        colidx[rowptr[d] + pos] = src[e];
    }
}

// ---------------------------------------------------------------- f32 -> bf16
__global__ __launch_bounds__(256) void kCvtX(const float4* __restrict__ x,
                                             uint2* __restrict__ xbf, int n4) {
    int i = blockIdx.x * 256 + threadIdx.x;
    if (i < n4) {
        float4 v = x[i];
        uint2 o;
        o.x = (unsigned int)f2bf(v.x) | ((unsigned int)f2bf(v.y) << 16);
        o.y = (unsigned int)f2bf(v.z) | ((unsigned int)f2bf(v.w) << 16);
        xbf[i] = o;
    }
}

// ------------------------------------------- pack [Wl;Wr] into MFMA B layout
// Bpack entry (t,c,l) = 8 bf16: B[k = t*32 + (l>>4)*8 + j][col = c*16 + (l&15)]
__global__ __launch_bounds__(256) void kPack(const float* __restrict__ Wl,
                                             const float* __restrict__ Wr,
                                             unsigned short* __restrict__ bpack) {
    int flat = blockIdx.x * 256 + threadIdx.x;       // 0..4095
    int t = flat >> 9, c = (flat >> 6) & 7, l = flat & 63;
    int col = c * 16 + (l & 15);
    int kbase = t * 32 + ((l >> 4) * 8);
    unsigned short vals[8];
#pragma unroll
    for (int j = 0; j < 8; ++j) {
        int krow = kbase + j;
        float w = (krow < 128) ? Wl[krow * 128 + col] : Wr[(krow - 128) * 128 + col];
        vals[j] = f2bf(w);
    }
    uint4 o;
    o.x = vals[0] | ((unsigned int)vals[1] << 16);
    o.y = vals[2] | ((unsigned int)vals[3] << 16);
    o.z = vals[4] | ((unsigned int)vals[5] << 16);
    o.w = vals[6] | ((unsigned int)vals[7] << 16);
    ((uint4*)bpack)[flat] = o;
}

// ---------------------------------------------------------- neighbor mean agg
__global__ __launch_bounds__(256) void kAgg(const unsigned short* __restrict__ feat,
                                            unsigned short* __restrict__ aggout,
                                            const int* __restrict__ rowptr,
                                            const int* __restrict__ colidx, int nNodes) {
    int w = threadIdx.x >> 6, l = threadIdx.x & 63;
    int node = blockIdx.x * 4 + w;
    if (node >= nNodes) return;
    int s = rowptr[node], e = rowptr[node + 1];
    float ax = 0.f, ay = 0.f;
    for (int base = s; base < e; base += 64) {
        int cnt = e - base; if (cnt > 64) cnt = 64;
        int myidx = (l < cnt) ? colidx[base + l] : 0;
        for (int j = 0; j < cnt; ++j) {
            int nbr = __shfl(myidx, j);
            unsigned int v = *(const unsigned int*)(feat + (size_t)nbr * D_F + l * 2);
            ax += bf2f((unsigned short)v);
            ay += bf2f((unsigned short)(v >> 16));
        }
    }
    int dg = e - s;
    float inv = 1.0f / (float)(dg > 0 ? dg : 1);
    unsigned int o = (unsigned int)f2bf(ax * inv) | ((unsigned int)f2bf(ay * inv) << 16);
    *(unsigned int*)(aggout + (size_t)node * D_F + l * 2) = o;
}

// -------------------- h = act([agg|x] @ [Wl;Wr] + b), bf16 MFMA, B in registers
__global__ __launch_bounds__(256) void kGemm(const unsigned short* __restrict__ Aagg,
                                             const unsigned short* __restrict__ Ax,
                                             const unsigned short* __restrict__ Bpack,
                                             const float* __restrict__ bias,
                                             unsigned short* __restrict__ Hout,
                                             int nrows, int relu) {
    int w = threadIdx.x >> 6, l = threadIdx.x & 63;
    int rowBase = blockIdx.x * 64;
    const uint4* bp = (const uint4*)Bpack;
    bf16x8 bfrag[8][2];
#pragma unroll
    for (int t = 0; t < 8; ++t)
#pragma unroll
        for (int c2 = 0; c2 < 2; ++c2) {
            int c = w * 2 + c2;
            U16B u; u.u = bp[(t * 8 + c) * 64 + l];
            bfrag[t][c2] = u.b;
        }
    f32x4 acc[4][2];
#pragma unroll
    for (int m = 0; m < 4; ++m)
#pragma unroll
        for (int c2 = 0; c2 < 2; ++c2) acc[m][c2] = (f32x4){0.f, 0.f, 0.f, 0.f};

    int lr = l & 15, lg = l >> 4;
    int arow[4];
#pragma unroll
    for (int m = 0; m < 4; ++m) {
        int r = rowBase + m * 16 + lr;
        arow[m] = r < nrows ? r : nrows - 1;
    }
#pragma unroll
    for (int t = 0; t < 8; ++t) {
        const unsigned short* src = (t < 4) ? Aagg : Ax;
        int kin = (t & 3) * 32 + lg * 8;
#pragma unroll
        for (int m = 0; m < 4; ++m) {
            U16B u; u.u = *(const uint4*)(src + (size_t)arow[m] * D_F + kin);
            acc[m][0] = __builtin_amdgcn_mfma_f32_16x16x32_bf16(u.b, bfrag[t][0], acc[m][0], 0, 0, 0);
            acc[m][1] = __builtin_amdgcn_mfma_f32_16x16x32_bf16(u.b, bfrag[t][1], acc[m][1], 0, 0, 0);
        }
    }
#pragma unroll
    for (int m = 0; m < 4; ++m)
#pragma unroll
        for (int c2 = 0; c2 < 2; ++c2) {
            int col = w * 32 + c2 * 16 + lr;
            float bz = bias[col];
#pragma unroll
            for (int r = 0; r < 4; ++r) {
                int row = rowBase + m * 16 + lg * 4 + r;
                if (row < nrows) {
                    float v = acc[m][c2][r] + bz;
                    if (relu) v = v > 0.f ? v : 0.f;
                    Hout[(size_t)row * D_F + col] = f2bf(v);
                }
            }
        }
}

// ------------- layer2 collapsed into pooling: S1[g] = sum_e (1/c_dst) h1[src]
__global__ __launch_bounds__(256) void kEdgePool(const unsigned short* __restrict__ feat,
                                                 const int* __restrict__ src,
                                                 const int* __restrict__ dst,
                                                 const int* __restrict__ batch,
                                                 const int* __restrict__ deg,
                                                 float* __restrict__ S1, int E) {
    __shared__ float lacc[4][NGRAPH][D_F];
    int w = threadIdx.x >> 6, l = threadIdx.x & 63;
    for (int i = threadIdx.x; i < 4 * NGRAPH * D_F; i += 256) ((float*)lacc)[i] = 0.f;
    __syncthreads();
    int gw = blockIdx.x * 4 + w;
    int stride = gridDim.x * 4;
    for (int e = gw; e < E; e += stride) {
        int s_ = src[e], d_ = dst[e];
        int g = batch[d_];
        int dg = deg[d_];
        float wg = 1.0f / (float)(dg > 0 ? dg : 1);
        unsigned int v = *(const unsigned int*)(feat + (size_t)s_ * D_F + l * 2);
        float2* p = (float2*)&lacc[w][g][l * 2];
        float2 cur = *p;
        cur.x += wg * bf2f((unsigned short)v);
        cur.y += wg * bf2f((unsigned short)(v >> 16));
        *p = cur;
    }
    __syncthreads();
    for (int i = threadIdx.x; i < NGRAPH * D_F; i += 256) {
        float sum = ((float*)lacc)[i] + ((float*)lacc)[2048 + i] +
                    ((float*)lacc)[4096 + i] + ((float*)lacc)[6144 + i];
        atomicAdd(&S1[i], sum);
    }
}

// S2[g] = sum_{n in g} h1[n];  nb[g] = |g|
__global__ __launch_bounds__(256) void kNodePool(const unsigned short* __restrict__ feat,
                                                 const int* __restrict__ batch,
                                                 float* __restrict__ S2,
                                                 int* __restrict__ nb, int nNodes) {
    __shared__ float lacc[4][NGRAPH][D_F];
    __shared__ int lcnt[4][NGRAPH];
    int w = threadIdx.x >> 6, l = threadIdx.x & 63;
    for (int i = threadIdx.x; i < 4 * NGRAPH * D_F; i += 256) ((float*)lacc)[i] = 0.f;
    if (threadIdx.x < 64) ((int*)lcnt)[threadIdx.x] = 0;
    __syncthreads();
    int gw = blockIdx.x * 4 + w, stride = gridDim.x * 4;
    for (int n = gw; n < nNodes; n += stride) {
        int g = batch[n];
        unsigned int v = *(const unsigned int*)(feat + (size_t)n * D_F + l * 2);
        float2* p = (float2*)&lacc[w][g][l * 2];
        float2 cur = *p;
        cur.x += bf2f((unsigned short)v);
        cur.y += bf2f((unsigned short)(v >> 16));
        *p = cur;
        if (l == 0) lcnt[w][g] += 1;
    }
    __syncthreads();
    for (int i = threadIdx.x; i < NGRAPH * D_F; i += 256) {
        float sum = ((float*)lacc)[i] + ((float*)lacc)[2048 + i] +
                    ((float*)lacc)[4096 + i] + ((float*)lacc)[6144 + i];
        atomicAdd(&S2[i], sum);
    }
    if (threadIdx.x < NGRAPH) {
        int c = lcnt[0][threadIdx.x] + lcnt[1][threadIdx.x] +
                lcnt[2][threadIdx.x] + lcnt[3][threadIdx.x];
        atomicAdd(&nb[threadIdx.x], c);
    }
}

// pooled = (S1/n) @ Wl2 + (S2/n) @ Wr2 + b2     (f32)
__global__ __launch_bounds__(128) void kPooled(const float* __restrict__ S1,
                                               const float* __restrict__ S2,
                                               const int* __restrict__ nb,
                                               const float* __restrict__ Wl2,
                                               const float* __restrict__ Wr2,
                                               const float* __restrict__ b2,
                                               float* __restrict__ pooled) {
    int b = blockIdx.x, k = threadIdx.x;
    int c = nb[b];
    float invn = 1.0f / (float)(c > 0 ? c : 1);
    float acc = b2[k];
    for (int d = 0; d < 128; ++d) {
        acc += S1[b * 128 + d] * invn * Wl2[d * 128 + k]
             + S2[b * 128 + d] * invn * Wr2[d * 128 + k];
    }
    pooled[b * 128 + k] = acc;
}

// nemb = pooled @ Wp + bp   (16 x 32768, f32)
__global__ __launch_bounds__(256) void kProj(const float* __restrict__ pooled,
                                             const float* __restrict__ Wp,
                                             const float* __restrict__ bp,
                                             float* __restrict__ nemb) {
    __shared__ float sp[NGRAPH * 128];
    for (int i = threadIdx.x; i < NGRAPH * 128; i += 256) sp[i] = pooled[i];
    __syncthreads();
    int k = blockIdx.x * 256 + threadIdx.x;   // 0..32767
    float acc[NGRAPH];
#pragma unroll
    for (int b = 0; b < NGRAPH; ++b) acc[b] = 0.f;
    for (int d = 0; d < 128; ++d) {
        float wv = Wp[(size_t)d * (NTOK * EMBED) + k];
#pragma unroll
        for (int b = 0; b < NGRAPH; ++b) acc[b] += sp[b * 128 + d] * wv;
    }
    float bk = bp[k];
#pragma unroll
    for (int b = 0; b < NGRAPH; ++b) nemb[(size_t)b * (NTOK * EMBED) + k] = acc[b] + bk;
}

// global prefix-sum rank of the is_node mask (B*S = 8192 entries)
__global__ __launch_bounds__(256) void kRank(const int* __restrict__ isn,
                                             int* __restrict__ rank) {
    __shared__ int ls[256];
    int t = threadIdx.x;
    int s = 0;
    for (int i = 0; i < 32; ++i) s += (isn[t * 32 + i] != 0);
    ls[t] = s; __syncthreads();
    for (int off = 1; off < 256; off <<= 1) {
        int v = (t >= off) ? ls[t - off] : 0;
        __syncthreads();
        ls[t] += v;
        __syncthreads();
    }
    int run = ls[t] - s;
    for (int i = 0; i < 32; ++i) {
        int p = t * 32 + i;
        int m = (isn[p] != 0);
        run += m;
        rank[p] = run - 1;
    }
}

// out[b,s,:] = mask ? nemb[rank] : embed_tokens[input_ids]
__global__ __launch_bounds__(256) void kAssemble(const float* __restrict__ embed,
                                                 const int* __restrict__ ids,
                                                 const int* __restrict__ isn,
                                                 const int* __restrict__ rank,
                                                 const float* __restrict__ nemb,
                                                 float4* __restrict__ out, int nvec) {
    int v = blockIdx.x * 256 + threadIdx.x;
    if (v >= nvec) return;
    int r = v >> 10;            // row in [0, B*S)  (1024 float4 per row)
    int c = v & 1023;
    const float4* sp;
    if (isn[r]) {
        int rk = rank[r];
        rk = rk < 0 ? 0 : (rk > NGRAPH * NTOK - 1 ? NGRAPH * NTOK - 1 : rk);
        sp = (const float4*)(nemb + (size_t)rk * EMBED);
    } else {
        sp = (const float4*)(embed + (size_t)ids[r] * EMBED);
    }
    out[v] = sp[c];
}

// ------------------------------------------------------------------ launcher
extern "C" void kernel_launch(void* const* d_in, const int* in_sizes, int n_in,
                              void* d_out, int out_size, void* d_ws, size_t ws_size,
                              hipStream_t stream) {
    (void)n_in; (void)ws_size;
    const float* x      = (const float*)d_in[0];
    const int*   eidx   = (const int*)d_in[1];
    const int*   batch  = (const int*)d_in[2];
    const int*   ids    = (const int*)d_in[3];
    const int*   isn    = (const int*)d_in[4];
    const float* embed  = (const float*)d_in[5];
    const float* Wl0 = (const float*)d_in[6],  *Wr0 = (const float*)d_in[7],  *b0 = (const float*)d_in[8];
    const float* Wl1 = (const float*)d_in[9],  *Wr1 = (const float*)d_in[10], *b1 = (const float*)d_in[11];
    const float* Wl2 = (const float*)d_in[12], *Wr2 = (const float*)d_in[13], *b2 = (const float*)d_in[14];
    const float* Wp  = (const float*)d_in[15], *bp  = (const float*)d_in[16];
    float* out = (float*)d_out;

    const int N = in_sizes[0] / D_F;   // 50000 nodes
    const int E = in_sizes[1] / 2;     // 800000 edges
    const int* srcI = eidx;
    const int* dstI = eidx + E;

    // ---- workspace layout (bump allocator, 256B aligned)
    char* ws = (char*)d_ws;
    size_t off = 0;
    auto alloc = [&](size_t bytes) { size_t o = off; off += (bytes + 255) & ~(size_t)255; return o; };
    size_t oDeg   = alloc((size_t)N * 4);
    size_t oRow   = alloc((size_t)(N + 1) * 4);
    size_t oFill  = alloc((size_t)N * 4);
    size_t oCol   = alloc((size_t)E * 4);
    size_t oBpack = alloc(8 * 8 * 64 * 8 * 2);           // 64 KiB
    size_t oS1    = alloc(NGRAPH * D_F * 4);
    size_t oS2    = alloc(NGRAPH * D_F * 4);
    size_t oNb    = alloc(256);
    size_t oPool  = alloc(NGRAPH * D_F * 4);
    size_t oRank  = alloc((size_t)NGRAPH * SEQ * 4);
    size_t oNemb  = alloc((size_t)NGRAPH * NTOK * EMBED * 4);
    size_t oXbf   = alloc((size_t)N * D_F * 2);          // also reused as h1
    size_t oAgg   = alloc((size_t)N * D_F * 2);
    size_t oH0    = alloc((size_t)N * D_F * 2);

    int*   deg    = (int*)(ws + oDeg);
    int*   rowptr = (int*)(ws + oRow);
    int*   fill   = (int*)(ws + oFill);
    int*   colidx = (int*)(ws + oCol);
    unsigned short* bpack = (unsigned short*)(ws + oBpack);
    float* S1     = (float*)(ws + oS1);
    float* S2     = (float*)(ws + oS2);
    int*   nb     = (int*)(ws + oNb);
    float* pooled = (float*)(ws + oPool);
    int*   rank   = (int*)(ws + oRank);
    float* nemb   = (float*)(ws + oNemb);
    unsigned short* xbf = (unsigned short*)(ws + oXbf);
    unsigned short* agg = (unsigned short*)(ws + oAgg);
    unsigned short* h0  = (unsigned short*)(ws + oH0);
    unsigned short* h1  = xbf;   // x dead after layer-0 GEMM; reuse

    // ---- zero the accumulated buffers (every call; ws is not re-poisoned)
    hipMemsetAsync(deg, 0, (size_t)N * 4, stream);
    hipMemsetAsync(fill, 0, (size_t)N * 4, stream);
    hipMemsetAsync(ws + oS1, 0, (oNb - oS1) + 256, stream);   // S1, S2, nb contiguous

    // ---- CSR
    kDeg <<<(E + 255) / 256, 256, 0, stream>>>(dstI, deg, E);
    kScan<<<1, 1024, 0, stream>>>(deg, rowptr, N);
    kFill<<<(E + 255) / 256, 256, 0, stream>>>(srcI, dstI, rowptr, fill, colidx, E);

    // ---- x -> bf16
    int n4 = in_sizes[0] / 4;
    kCvtX<<<(n4 + 255) / 256, 256, 0, stream>>>((const float4*)x, (uint2*)xbf, n4);

    // ---- layer 0
    kPack<<<16, 256, 0, stream>>>(Wl0, Wr0, bpack);
    kAgg <<<(N + 3) / 4, 256, 0, stream>>>(xbf, agg, rowptr, colidx, N);
    kGemm<<<(N + 63) / 64, 256, 0, stream>>>(agg, xbf, bpack, b0, h0, N, 1);

    // ---- layer 1
    kPack<<<16, 256, 0, stream>>>(Wl1, Wr1, bpack);
    kAgg <<<(N + 3) / 4, 256, 0, stream>>>(h0, agg, rowptr, colidx, N);
    kGemm<<<(N + 63) / 64, 256, 0, stream>>>(agg, h0, bpack, b1, h1, N, 1);

    // ---- layer 2 fused with mean-pool
    kEdgePool<<<1024, 256, 0, stream>>>(h1, srcI, dstI, batch, deg, S1, E);
    kNodePool<<<256, 256, 0, stream>>>(h1, batch, S2, nb, N);
    kPooled<<<NGRAPH, 128, 0, stream>>>(S1, S2, nb, Wl2, Wr2, b2, pooled);

    // ---- projection to graph tokens
    kProj<<<(NTOK * EMBED) / 256, 256, 0, stream>>>(pooled, Wp, bp, nemb);

    // ---- mask ranks + final assembly
    kRank<<<1, 256, 0, stream>>>(isn, rank);
    int nvec = out_size / 4;
    kAssemble<<<(nvec + 255) / 256, 256, 0, stream>>>(embed, ids, isn, rank, nemb,
                                                      (float4*)out, nvec);
}

// Round 2
// 349.740 us; speedup vs baseline: 1.6753x; 1.6753x over previous
//
#include <hip/hip_runtime.h>
#include <stdint.h>

#define D_F    128
#define NGRAPH 16
#define SEQ    512
#define NTOK   8
#define EMBED  4096

typedef __bf16 bf16_t;
typedef __attribute__((ext_vector_type(8))) bf16_t bf16x8;
typedef __attribute__((ext_vector_type(4))) float f32x4;

union U16B { uint4 u; bf16x8 b; };

static __device__ __forceinline__ unsigned short f2bf(float f) {
    unsigned int u = __float_as_uint(f);
    u += 0x7fffu + ((u >> 16) & 1u);          // round-to-nearest-even
    return (unsigned short)(u >> 16);
}
static __device__ __forceinline__ float bf2f(unsigned short s) {
    return __uint_as_float(((unsigned int)s) << 16);
}

static __device__ __forceinline__ int waveInclScan(int v, int lane) {
#pragma unroll
    for (int off = 1; off < 64; off <<= 1) {
        int u = __shfl_up(v, off);
        if (lane >= off) v += u;
    }
    return v;
}

// ============================ fused prep: deg-count | f32->bf16 | weight pack
__global__ __launch_bounds__(256) void kPrep(const int* __restrict__ dst,
                                             int* __restrict__ deg, int E,
                                             const float4* __restrict__ x,
                                             uint2* __restrict__ xbf, int n4,
                                             const float* __restrict__ Wl0,
                                             const float* __restrict__ Wr0,
                                             unsigned short* __restrict__ bp0,
                                             const float* __restrict__ Wl1,
                                             const float* __restrict__ Wr1,
                                             unsigned short* __restrict__ bp1,
                                             int nbDeg, int nbCvt) {
    int b = blockIdx.x;
    if (b < nbDeg) {
        int t = b * 256 + threadIdx.x;
        int e0 = t * 4;
        if (e0 + 3 < E) {
            int4 d4 = ((const int4*)dst)[t];
            atomicAdd(&deg[d4.x], 1); atomicAdd(&deg[d4.y], 1);
            atomicAdd(&deg[d4.z], 1); atomicAdd(&deg[d4.w], 1);
        } else {
            for (int k = 0; k < 4; ++k) { int e = e0 + k; if (e < E) atomicAdd(&deg[dst[e]], 1); }
        }
    } else if (b < nbDeg + nbCvt) {
        int i = (b - nbDeg) * 256 + threadIdx.x;
        if (i < n4) {
            float4 v = x[i];
            uint2 o;
            o.x = (unsigned int)f2bf(v.x) | ((unsigned int)f2bf(v.y) << 16);
            o.y = (unsigned int)f2bf(v.z) | ((unsigned int)f2bf(v.w) << 16);
            xbf[i] = o;
        }
    } else {
        int pb = b - nbDeg - nbCvt;                  // 0..31
        const float* Wl = (pb < 16) ? Wl0 : Wl1;
        const float* Wr = (pb < 16) ? Wr0 : Wr1;
        unsigned short* bp = (pb < 16) ? bp0 : bp1;
        int flat = (pb & 15) * 256 + threadIdx.x;    // 0..4095
        int t = flat >> 9, c = (flat >> 6) & 7, l = flat & 63;
        int col = c * 16 + (l & 15);
        int kbase = t * 32 + ((l >> 4) * 8);
        unsigned short vals[8];
#pragma unroll
        for (int j = 0; j < 8; ++j) {
            int krow = kbase + j;
            float w = (krow < 128) ? Wl[krow * 128 + col] : Wr[(krow - 128) * 128 + col];
            vals[j] = f2bf(w);
        }
        uint4 o;
        o.x = vals[0] | ((unsigned int)vals[1] << 16);
        o.y = vals[2] | ((unsigned int)vals[3] << 16);
        o.z = vals[4] | ((unsigned int)vals[5] << 16);
        o.w = vals[6] | ((unsigned int)vals[7] << 16);
        ((uint4*)bp)[flat] = o;
    }
}

// ==================== block 0: rowptr scan (int4, wave scans); block 1: rank
__global__ __launch_bounds__(1024) void kScanRank(const int* __restrict__ deg,
                                                  int* __restrict__ rowptr, int N,
                                                  const int* __restrict__ isn,
                                                  int* __restrict__ rank) {
    __shared__ int lsum[16];
    int t = threadIdx.x, lane = t & 63, wid = t >> 6;
    if (blockIdx.x == 0) {
        int NV4 = N >> 2;                    // N % 4 == 0 (50000)
        int rounds = (NV4 + 1023) / 1024;
        int carry = 0;
        for (int r = 0; r < rounds; ++r) {
            int idx = r * 1024 + t;
            int4 v = {0, 0, 0, 0};
            if (idx < NV4) v = ((const int4*)deg)[idx];
            int s = v.x + v.y + v.z + v.w;
            int inc = waveInclScan(s, lane);
            if (lane == 63) lsum[wid] = inc;
            __syncthreads();
            if (t < 16) {
                int vv = lsum[t];
#pragma unroll
                for (int off = 1; off < 16; off <<= 1) {
                    int u = __shfl_up(vv, off);
                    if (t >= off) vv += u;
                }
                lsum[t] = vv;
            }
            __syncthreads();
            int wexc = wid ? lsum[wid - 1] : 0;
            int total = lsum[15];
            int excl = carry + wexc + inc - s;
            if (idx < NV4) {
                int4 o;
                o.x = excl; o.y = excl + v.x; o.z = o.y + v.y; o.w = o.z + v.z;
                ((int4*)rowptr)[idx] = o;
            }
            carry += total;
            __syncthreads();
        }
        if (t == 0) rowptr[N] = carry;
    } else {
        // rank of is_node mask over B*S = 8192 entries, 8 per thread
        int4 a = ((const int4*)isn)[t * 2];
        int4 bq = ((const int4*)isn)[t * 2 + 1];
        int m[8];
        m[0] = a.x != 0;  m[1] = a.y != 0;  m[2] = a.z != 0;  m[3] = a.w != 0;
        m[4] = bq.x != 0; m[5] = bq.y != 0; m[6] = bq.z != 0; m[7] = bq.w != 0;
        int s = 0;
#pragma unroll
        for (int i = 0; i < 8; ++i) s += m[i];
        int inc = waveInclScan(s, lane);
        if (lane == 63) lsum[wid] = inc;
        __syncthreads();
        if (t < 16) {
            int vv = lsum[t];
#pragma unroll
            for (int off = 1; off < 16; off <<= 1) {
                int u = __shfl_up(vv, off);
                if (t >= off) vv += u;
            }
            lsum[t] = vv;
        }
        __syncthreads();
        int excl = (wid ? lsum[wid - 1] : 0) + inc - s;
        int run = excl;
#pragma unroll
        for (int i = 0; i < 8; ++i) { run += m[i]; rank[t * 8 + i] = run - 1; }
    }
}

// =========================================================== CSR column fill
__global__ __launch_bounds__(256) void kFill(const int* __restrict__ src,
                                             const int* __restrict__ dst,
                                             const int* __restrict__ rowptr,
                                             int* __restrict__ fill,
                                             int* __restrict__ colidx, int E) {
    int t = blockIdx.x * 256 + threadIdx.x;
    int e0 = t * 4;
    if (e0 + 3 < E) {
        int4 s4 = ((const int4*)src)[t];
        int4 d4 = ((const int4*)dst)[t];
        int p;
        p = atomicAdd(&fill[d4.x], 1); colidx[rowptr[d4.x] + p] = s4.x;
        p = atomicAdd(&fill[d4.y], 1); colidx[rowptr[d4.y] + p] = s4.y;
        p = atomicAdd(&fill[d4.z], 1); colidx[rowptr[d4.z] + p] = s4.z;
        p = atomicAdd(&fill[d4.w], 1); colidx[rowptr[d4.w] + p] = s4.w;
    } else {
        for (int k = 0; k < 4; ++k) {
            int e = e0 + k;
            if (e < E) {
                int d = dst[e];
                int p = atomicAdd(&fill[d], 1);
                colidx[rowptr[d] + p] = src[e];
            }
        }
    }
}

// ============ neighbor mean: wave per node, 2 edges/iter, 4 loads in flight
__global__ __launch_bounds__(256) void kAgg(const unsigned short* __restrict__ feat,
                                            unsigned short* __restrict__ aggout,
                                            const int* __restrict__ rowptr,
                                            const int* __restrict__ colidx, int nNodes) {
    int w = threadIdx.x >> 6, l = threadIdx.x & 63;
    int node = blockIdx.x * 4 + w;
    if (node >= nNodes) return;
    int s = rowptr[node], e = rowptr[node + 1];
    int h = l >> 5, c = l & 31;               // half-wave h covers edge parity
    float ax = 0.f, ay = 0.f, az = 0.f, aw = 0.f;
    for (int base = s; base < e; base += 64) {
        int cnt = e - base; if (cnt > 64) cnt = 64;
        int myidx = (l < cnt) ? colidx[base + l] : 0;
        int j = 0;
        for (; j + 4 <= cnt; j += 4) {
            int n0 = __shfl(myidx, j + h);
            int n1 = __shfl(myidx, j + 2 + h);
            uint2 u0 = *(const uint2*)(feat + (size_t)n0 * D_F + c * 4);
            uint2 u1 = *(const uint2*)(feat + (size_t)n1 * D_F + c * 4);
            ax += bf2f((unsigned short)u0.x) + bf2f((unsigned short)u1.x);
            ay += bf2f((unsigned short)(u0.x >> 16)) + bf2f((unsigned short)(u1.x >> 16));
            az += bf2f((unsigned short)u0.y) + bf2f((unsigned short)u1.y);
            aw += bf2f((unsigned short)(u0.y >> 16)) + bf2f((unsigned short)(u1.y >> 16));
        }
        for (; j < cnt; j += 2) {
            int jj = j + h;
            if (jj < cnt) {
                int n0 = __shfl(myidx, jj);
                uint2 u0 = *(const uint2*)(feat + (size_t)n0 * D_F + c * 4);
                ax += bf2f((unsigned short)u0.x);
                ay += bf2f((unsigned short)(u0.x >> 16));
                az += bf2f((unsigned short)u0.y);
                aw += bf2f((unsigned short)(u0.y >> 16));
            }
        }
    }
    // combine the two edge-parity halves (lanes l and l^32 hold the same dims)
    ax += __shfl_xor(ax, 32);
    ay += __shfl_xor(ay, 32);
    az += __shfl_xor(az, 32);
    aw += __shfl_xor(aw, 32);
    int dg = e - s;
    float inv = 1.0f / (float)(dg > 0 ? dg : 1);
    if (h == 0) {
        uint2 o;
        o.x = (unsigned int)f2bf(ax * inv) | ((unsigned int)f2bf(ay * inv) << 16);
        o.y = (unsigned int)f2bf(az * inv) | ((unsigned int)f2bf(aw * inv) << 16);
        *(uint2*)(aggout + (size_t)node * D_F + c * 4) = o;
    }
}

// ======== h = act([agg|x] @ [Wl;Wr] + b), bf16 MFMA, B fragments in registers
__global__ __launch_bounds__(256) void kGemm(const unsigned short* __restrict__ Aagg,
                                             const unsigned short* __restrict__ Ax,
                                             const unsigned short* __restrict__ Bpack,
                                             const float* __restrict__ bias,
                                             unsigned short* __restrict__ Hout,
                                             int nrows, int relu) {
    int w = threadIdx.x >> 6, l = threadIdx.x & 63;
    int rowBase = blockIdx.x * 64;
    const uint4* bp = (const uint4*)Bpack;
    bf16x8 bfrag[8][2];
#pragma unroll
    for (int t = 0; t < 8; ++t)
#pragma unroll
        for (int c2 = 0; c2 < 2; ++c2) {
            int c = w * 2 + c2;
            U16B u; u.u = bp[(t * 8 + c) * 64 + l];
            bfrag[t][c2] = u.b;
        }
    f32x4 acc[4][2];
#pragma unroll
    for (int m = 0; m < 4; ++m)
#pragma unroll
        for (int c2 = 0; c2 < 2; ++c2) acc[m][c2] = (f32x4){0.f, 0.f, 0.f, 0.f};

    int lr = l & 15, lg = l >> 4;
    int arow[4];
#pragma unroll
    for (int m = 0; m < 4; ++m) {
        int r = rowBase + m * 16 + lr;
        arow[m] = r < nrows ? r : nrows - 1;
    }
#pragma unroll
    for (int t = 0; t < 8; ++t) {
        const unsigned short* srcp = (t < 4) ? Aagg : Ax;
        int kin = (t & 3) * 32 + lg * 8;
#pragma unroll
        for (int m = 0; m < 4; ++m) {
            U16B u; u.u = *(const uint4*)(srcp + (size_t)arow[m] * D_F + kin);
            acc[m][0] = __builtin_amdgcn_mfma_f32_16x16x32_bf16(u.b, bfrag[t][0], acc[m][0], 0, 0, 0);
            acc[m][1] = __builtin_amdgcn_mfma_f32_16x16x32_bf16(u.b, bfrag[t][1], acc[m][1], 0, 0, 0);
        }
    }
#pragma unroll
    for (int m = 0; m < 4; ++m)
#pragma unroll
        for (int c2 = 0; c2 < 2; ++c2) {
            int col = w * 32 + c2 * 16 + lr;
            float bz = bias[col];
#pragma unroll
            for (int r = 0; r < 4; ++r) {
                int row = rowBase + m * 16 + lg * 4 + r;
                if (row < nrows) {
                    float v = acc[m][c2][r] + bz;
                    if (relu) v = v > 0.f ? v : 0.f;
                    Hout[(size_t)row * D_F + col] = f2bf(v);
                }
            }
        }
}

// ===== pooled sums: S1 += agg2[n], S2 += h1[n], nb[g]++ over nodes (one pass)
__global__ __launch_bounds__(256) void kPool(const unsigned short* __restrict__ h1,
                                             const unsigned short* __restrict__ agg2,
                                             const int* __restrict__ batch,
                                             float* __restrict__ S1,
                                             float* __restrict__ S2,
                                             int* __restrict__ nb, int nNodes) {
    __shared__ float l1[4][NGRAPH * D_F];     // 32 KiB
    __shared__ float l2[4][NGRAPH * D_F];     // 32 KiB
    __shared__ int lcnt[4][NGRAPH];
    int w = threadIdx.x >> 6, l = threadIdx.x & 63;
    for (int i = threadIdx.x; i < 4 * NGRAPH * D_F; i += 256) {
        ((float*)l1)[i] = 0.f; ((float*)l2)[i] = 0.f;
    }
    if (threadIdx.x < 64) ((int*)lcnt)[threadIdx.x] = 0;
    __syncthreads();
    int stride = gridDim.x * 4;
    for (int n = blockIdx.x * 4 + w; n < nNodes; n += stride) {
        int g = batch[n];
        unsigned int va = *(const unsigned int*)(agg2 + (size_t)n * D_F + l * 2);
        unsigned int vh = *(const unsigned int*)(h1 + (size_t)n * D_F + l * 2);
        float2* p1 = (float2*)&l1[w][g * D_F + l * 2];
        float2* p2 = (float2*)&l2[w][g * D_F + l * 2];
        float2 c1 = *p1, c2v = *p2;
        c1.x += bf2f((unsigned short)va);        c1.y += bf2f((unsigned short)(va >> 16));
        c2v.x += bf2f((unsigned short)vh);       c2v.y += bf2f((unsigned short)(vh >> 16));
        *p1 = c1; *p2 = c2v;
        if (l == 0) lcnt[w][g] += 1;
    }
    __syncthreads();
    for (int i = threadIdx.x; i < NGRAPH * D_F; i += 256) {
        float s1 = l1[0][i] + l1[1][i] + l1[2][i] + l1[3][i];
        float s2 = l2[0][i] + l2[1][i] + l2[2][i] + l2[3][i];
        atomicAdd(&S1[i], s1);
        atomicAdd(&S2[i], s2);
    }
    if (threadIdx.x < NGRAPH) {
        int c = lcnt[0][threadIdx.x] + lcnt[1][threadIdx.x] +
                lcnt[2][threadIdx.x] + lcnt[3][threadIdx.x];
        atomicAdd(&nb[threadIdx.x], c);
    }
}

// pooled = (S1/n) @ Wl2 + (S2/n) @ Wr2 + b2     (f32)
__global__ __launch_bounds__(128) void kPooled(const float* __restrict__ S1,
                                               const float* __restrict__ S2,
                                               const int* __restrict__ nb,
                                               const float* __restrict__ Wl2,
                                               const float* __restrict__ Wr2,
                                               const float* __restrict__ b2,
                                               float* __restrict__ pooled) {
    int b = blockIdx.x, k = threadIdx.x;
    int c = nb[b];
    float invn = 1.0f / (float)(c > 0 ? c : 1);
    float acc = b2[k];
    for (int d = 0; d < 128; ++d) {
        acc += S1[b * 128 + d] * invn * Wl2[d * 128 + k]
             + S2[b * 128 + d] * invn * Wr2[d * 128 + k];
    }
    pooled[b * 128 + k] = acc;
}

// nemb = pooled @ Wp + bp   (16 x 32768, f32)
__global__ __launch_bounds__(256) void kProj(const float* __restrict__ pooled,
                                             const float* __restrict__ Wp,
                                             const float* __restrict__ bp,
                                             float* __restrict__ nemb) {
    __shared__ float sp[NGRAPH * 128];
    for (int i = threadIdx.x; i < NGRAPH * 128; i += 256) sp[i] = pooled[i];
    __syncthreads();
    int k = blockIdx.x * 256 + threadIdx.x;   // 0..32767
    float acc[NGRAPH];
#pragma unroll
    for (int b = 0; b < NGRAPH; ++b) acc[b] = 0.f;
    for (int d = 0; d < 128; ++d) {
        float wv = Wp[(size_t)d * (NTOK * EMBED) + k];
#pragma unroll
        for (int b = 0; b < NGRAPH; ++b) acc[b] += sp[b * 128 + d] * wv;
    }
    float bk = bp[k];
#pragma unroll
    for (int b = 0; b < NGRAPH; ++b) nemb[(size_t)b * (NTOK * EMBED) + k] = acc[b] + bk;
}

// out[b,s,:] = mask ? nemb[rank] : embed_tokens[input_ids]   (32 B / thread)
__global__ __launch_bounds__(256) void kAssemble(const float* __restrict__ embed,
                                                 const int* __restrict__ ids,
                                                 const int* __restrict__ isn,
                                                 const int* __restrict__ rank,
                                                 const float* __restrict__ nemb,
                                                 float4* __restrict__ out, int nvec2) {
    int v = blockIdx.x * 256 + threadIdx.x;
    if (v >= nvec2) return;
    int r = v >> 9;                 // 512 threads per row of 4096 floats
    int c = (v & 511) * 2;          // float4 index within row
    const float4* sp;
    if (isn[r]) {
        int rk = rank[r];
        rk = rk < 0 ? 0 : (rk > NGRAPH * NTOK - 1 ? NGRAPH * NTOK - 1 : rk);
        sp = (const float4*)(nemb + (size_t)rk * EMBED);
    } else {
        sp = (const float4*)(embed + (size_t)ids[r] * EMBED);
    }
    float4 a = sp[c];
    float4 b = sp[c + 1];
    out[(size_t)v * 2]     = a;
    out[(size_t)v * 2 + 1] = b;
}

// ------------------------------------------------------------------ launcher
extern "C" void kernel_launch(void* const* d_in, const int* in_sizes, int n_in,
                              void* d_out, int out_size, void* d_ws, size_t ws_size,
                              hipStream_t stream) {
    (void)n_in; (void)ws_size;
    const float* x      = (const float*)d_in[0];
    const int*   eidx   = (const int*)d_in[1];
    const int*   batch  = (const int*)d_in[2];
    const int*   ids    = (const int*)d_in[3];
    const int*   isn    = (const int*)d_in[4];
    const float* embed  = (const float*)d_in[5];
    const float* Wl0 = (const float*)d_in[6],  *Wr0 = (const float*)d_in[7],  *b0 = (const float*)d_in[8];
    const float* Wl1 = (const float*)d_in[9],  *Wr1 = (const float*)d_in[10], *b1 = (const float*)d_in[11];
    const float* Wl2 = (const float*)d_in[12], *Wr2 = (const float*)d_in[13], *b2 = (const float*)d_in[14];
    const float* Wp  = (const float*)d_in[15], *bp  = (const float*)d_in[16];
    float* out = (float*)d_out;

    const int N = in_sizes[0] / D_F;   // 50000
    const int E = in_sizes[1] / 2;     // 800000
    const int* srcI = eidx;
    const int* dstI = eidx + E;

    // ---- workspace (bump allocator, 256 B aligned); deg..nb contiguous for 1 memset
    char* ws = (char*)d_ws;
    size_t off = 0;
    auto alloc = [&](size_t bytes) { size_t o = off; off += (bytes + 255) & ~(size_t)255; return o; };
    size_t oDeg   = alloc((size_t)N * 4);
    size_t oFill  = alloc((size_t)N * 4);
    size_t oS1    = alloc(NGRAPH * D_F * 4);
    size_t oS2    = alloc(NGRAPH * D_F * 4);
    size_t oNb    = alloc(256);
    size_t oRow   = alloc((size_t)(N + 1) * 4);
    size_t oCol   = alloc((size_t)E * 4);
    size_t oBp0   = alloc(8 * 8 * 64 * 8 * 2);
    size_t oBp1   = alloc(8 * 8 * 64 * 8 * 2);
    size_t oPool  = alloc(NGRAPH * D_F * 4);
    size_t oRank  = alloc((size_t)NGRAPH * SEQ * 4);
    size_t oNemb  = alloc((size_t)NGRAPH * NTOK * EMBED * 4);
    size_t oXbf   = alloc((size_t)N * D_F * 2);
    size_t oAgg   = alloc((size_t)N * D_F * 2);
    size_t oH0    = alloc((size_t)N * D_F * 2);

    int*   deg    = (int*)(ws + oDeg);
    int*   fill   = (int*)(ws + oFill);
    float* S1     = (float*)(ws + oS1);
    float* S2     = (float*)(ws + oS2);
    int*   nb     = (int*)(ws + oNb);
    int*   rowptr = (int*)(ws + oRow);
    int*   colidx = (int*)(ws + oCol);
    unsigned short* bp0 = (unsigned short*)(ws + oBp0);
    unsigned short* bp1 = (unsigned short*)(ws + oBp1);
    float* pooled = (float*)(ws + oPool);
    int*   rank   = (int*)(ws + oRank);
    float* nemb   = (float*)(ws + oNemb);
    unsigned short* xbf = (unsigned short*)(ws + oXbf);
    unsigned short* agg = (unsigned short*)(ws + oAgg);
    unsigned short* h0  = (unsigned short*)(ws + oH0);
    unsigned short* h1  = xbf;   // x dead after layer-0 GEMM; reuse

    // one memset covers deg, fill, S1, S2, nb (contiguous)
    hipMemsetAsync(ws + oDeg, 0, (oNb - oDeg) + 256, stream);

    int n4 = in_sizes[0] / 4;                      // 1.6 M float4
    int nbDeg = ((E + 3) / 4 + 255) / 256;         // 782
    int nbCvt = (n4 + 255) / 256;                  // 6250
    kPrep<<<nbDeg + nbCvt + 32, 256, 0, stream>>>(dstI, deg, E, (const float4*)x,
                                                  (uint2*)xbf, n4,
                                                  Wl0, Wr0, bp0, Wl1, Wr1, bp1,
                                                  nbDeg, nbCvt);
    kScanRank<<<2, 1024, 0, stream>>>(deg, rowptr, N, isn, rank);
    kFill<<<nbDeg, 256, 0, stream>>>(srcI, dstI, rowptr, fill, colidx, E);

    // layer 0
    kAgg <<<(N + 3) / 4, 256, 0, stream>>>(xbf, agg, rowptr, colidx, N);
    kGemm<<<(N + 63) / 64, 256, 0, stream>>>(agg, xbf, bp0, b0, h0, N, 1);
    // layer 1
    kAgg <<<(N + 3) / 4, 256, 0, stream>>>(h0, agg, rowptr, colidx, N);
    kGemm<<<(N + 63) / 64, 256, 0, stream>>>(agg, h0, bp1, b1, h1, N, 1);
    // layer 2 aggregation (feeds pooled sums; Wl2/Wr2 applied after pooling)
    kAgg <<<(N + 3) / 4, 256, 0, stream>>>(h1, agg, rowptr, colidx, N);
    kPool<<<256, 256, 0, stream>>>(h1, agg, batch, S1, S2, nb, N);
    kPooled<<<NGRAPH, 128, 0, stream>>>(S1, S2, nb, Wl2, Wr2, b2, pooled);

    // projection + assembly
    kProj<<<(NTOK * EMBED) / 256, 256, 0, stream>>>(pooled, Wp, bp, nemb);
    int nvec2 = out_size / 8;
    kAssemble<<<(nvec2 + 255) / 256, 256, 0, stream>>>(embed, ids, isn, rank, nemb,
                                                       (float4*)out, nvec2);
}